// Round 10
// baseline (2502.946 us; speedup 1.0000x reference)
//
#include <hip/hip_runtime.h>

#define NIN 10517

__device__ __forceinline__ float lrelu02(float x){ return x > 0.f ? x : 0.2f*x; }
__device__ __forceinline__ float fast_tanh(float x){ float e=__expf(2.f*x); return 1.f - 2.f/(e+1.f); }
__device__ __forceinline__ float fast_sig(float x){ return 1.f/(1.f+__expf(-x)); }

// lane l gets partial[l] + partial[l^32] (validated round 4). Result is
// guaranteed on the p==0 lanes; all LDS/global writes are gated on p==0.
__device__ __forceinline__ float half_reduce(float a){
  float s;
  asm volatile("v_mov_b32 %0, %1\n\t"
               "v_permlane32_swap_b32 %0, %1\n\t"
               "v_add_f32 %0, %0, %1"
               : "=&v"(s), "+v"(a));
  return s;
}

// light barrier: order LDS writes->reads without draining vmcnt (weight/gi
// loads and hs stores float across phases)
#define LBAR() do { asm volatile("s_waitcnt lgkmcnt(0)" ::: "memory"); \
                    __builtin_amdgcn_s_barrier(); } while (0)

// ---------------- K1a: FC + Wh0 + s,d  (k_prep transposes folded in) ----------------
__global__ __launch_bounds__(256) void k_fc_gat(const float* __restrict__ inputs,
    const float* __restrict__ fc_w, const float* __restrict__ fc_b,
    const float* __restrict__ gat_w, const float* __restrict__ a_src, const float* __restrict__ a_dst,
    const float* __restrict__ ode_w1, const float* __restrict__ ode_w2, const float* __restrict__ gru_wh,
    float* __restrict__ wh0_ws, float* __restrict__ sd_ws,
    float* __restrict__ w1T, float* __restrict__ w2T, float* __restrict__ ghT)
{
  __shared__ float xin[16][384];
  __shared__ float xfc[16][256];
  __shared__ float wh[16][128];
  const int tid = threadIdx.x;
  const int bt0 = blockIdx.x * 16;

  // folded k_prep: weight transposes (independent of the rest)
  {
    int gidx = blockIdx.x * 256 + tid;            // 0..32767
    for (int idx = gidx; idx < 384*128; idx += 128*256) {
      int m = idx >> 7, k = idx & 127;
      ghT[idx] = gru_wh[k*384 + m];
    }
    if (gidx < 128*128) {
      int jj = gidx >> 7, k = gidx & 127;
      w1T[gidx] = ode_w1[k*128 + jj];
      w2T[gidx] = ode_w2[k*128 + jj];
    }
  }

  for (int idx = tid; idx < 16*384; idx += 256) {
    int r = idx / 384, f = idx - r*384;
    xin[r][f] = inputs[(size_t)(bt0+r)*NIN + 10133 + f];
  }
  __syncthreads();
  {
    float acc[16];
    float bj = fc_b[tid];
    #pragma unroll
    for (int r=0;r<16;r++) acc[r] = bj;
    for (int f=0; f<384; f++) {
      float wf = fc_w[f*256 + tid];
      #pragma unroll
      for (int r=0;r<16;r++) acc[r] = fmaf(xin[r][f], wf, acc[r]);
    }
    #pragma unroll
    for (int r=0;r<16;r++) xfc[r][tid] = fmaxf(acc[r], 0.f);
  }
  __syncthreads();
  {
    const int j2 = tid & 127, r0 = (tid >> 7) * 8;
    float acc[8];
    #pragma unroll
    for (int r=0;r<8;r++) acc[r] = 0.f;
    for (int f=0; f<256; f++) {
      float wf = gat_w[f*128 + j2];
      #pragma unroll
      for (int r=0;r<8;r++) acc[r] = fmaf(xfc[r0+r][f], wf, acc[r]);
    }
    #pragma unroll
    for (int r=0;r<8;r++) {
      wh[r0+r][j2] = acc[r];
      wh0_ws[(size_t)(bt0+r0+r)*128 + j2] = acc[r];
    }
  }
  __syncthreads();
  if (tid < 128) {
    const int r = tid >> 3, h = (tid >> 1) & 3, w = tid & 1;
    const float* av = w ? a_dst : a_src;
    float acc = 0.f;
    #pragma unroll
    for (int d=0; d<32; d++) acc = fmaf(wh[r][h*32+d], av[h*32+d], acc);
    sd_ws[(size_t)(bt0+r)*8 + w*4 + h] = acc;
  }
}

// ---------------- K1b: adjacency stats + closed-form alpha + x_gat + gi ----------------
__global__ __launch_bounds__(256) void k_alpha_gi(const float* __restrict__ inputs,
    const float* __restrict__ wh0_ws, const float* __restrict__ sd_ws,
    const float* __restrict__ gru_wi, const float* __restrict__ gru_bi,
    float* __restrict__ gi_ws)
{
  __shared__ int cnt[100];
  __shared__ int a0f[100];
  __shared__ float alpha[4][100];
  __shared__ float wh0[128];
  __shared__ float sdl[8];
  __shared__ float xg[128];
  __shared__ float psum[256];
  const int tid = threadIdx.x;
  const size_t bt = blockIdx.x;
  if (tid < 128) wh0[tid] = wh0_ws[bt*128 + tid];
  if (tid < 8) sdl[tid] = sd_ws[bt*8 + tid];
  const float* adj = inputs + bt*NIN + 132;
  const int wv = tid >> 6, lane = tid & 63;
  for (int i = wv; i < 100; i += 4) {
    float v0 = adj[i*100 + lane];
    int pred0 = (lane != 0) && ((v0 > 0.f) || (lane == i));
    unsigned long long b0 = __ballot(pred0);
    int pred1 = 0;
    if (lane < 36) {
      float v1 = adj[i*100 + 64 + lane];
      pred1 = (v1 > 0.f) || ((64 + lane) == i);
    }
    unsigned long long b1 = __ballot(pred1);
    if (lane == 0) {
      cnt[i] = __popcll(b0) + __popcll(b1);
      a0f[i] = (v0 > 0.f) ? 1 : 0;
    }
  }
  __syncthreads();
  for (int idx = tid; idx < 400; idx += 256) {
    int h = idx / 100, i = idx - h*100;
    float s = sdl[h], d = sdl[4+h];
    float a;
    if (i == 0) {
      float ea = __expf(lrelu02(s + d));
      float eb = __expf(lrelu02(s));
      a = ea / (ea + (float)cnt[0] * eb);
    } else if (a0f[i]) {
      float ed = __expf(lrelu02(d));
      a = ed / (ed + (float)cnt[i]);
    } else {
      a = 0.f;
    }
    alpha[h][i] = a;
  }
  __syncthreads();
  // elu + mean, split across all 256 threads (2 per (h,d) pair)
  {
    const int pr = tid & 127, hf = tid >> 7;
    const float w = wh0[pr];
    const int hh = pr >> 5;
    float sum = 0.f;
    const int i0 = hf * 50;
    for (int i = i0; i < i0 + 50; i++) {
      float t = alpha[hh][i] * w;
      sum += (t > 0.f) ? t : (__expf(t) - 1.f);
    }
    psum[tid] = sum;
  }
  __syncthreads();
  if (tid < 128) xg[tid] = (psum[tid] + psum[tid+128]) * 0.01f;
  __syncthreads();
  for (int jj = tid; jj < 384; jj += 256) {
    float acc = gru_bi[jj];
    for (int f=0; f<128; f++) acc = fmaf(xg[f], gru_wi[f*384 + jj], acc);
    gi_ws[bt*384 + jj] = acc;
  }
}

// ---------------- K2: RK4-ODE + GRU scan, TWIN-CHAIN ----------------
// 16 blocks x 512 threads. Waves 0-3 process batch element 2b, waves 4-7
// element 2b+1 (independent dependency chains). HW places wave w on SIMD w%4
// -> each SIMD hosts one wave of EACH chain: while chain A stalls on
// ds_read/L2/tanh latency, chain B issues FMAs. The shared barrier couples
// two identical workloads (benign skew). Within a chain: col j = wave*32 +
// (lane&31), K-half p = lane>>5, permlane32 reduce (validated r4).
__global__ __launch_bounds__(512) void k_rnn(const float* __restrict__ inputs,
    const float* __restrict__ h0,
    const float* __restrict__ w1T, const float* __restrict__ ode_b1,
    const float* __restrict__ w2T, const float* __restrict__ ode_b2,
    const float* __restrict__ ghT, const float* __restrict__ gru_bh,
    const float* __restrict__ gi_ws, float* __restrict__ hs_ws, float* __restrict__ hT_out)
{
  __shared__ __align__(16) float Abuf[2][136];
  __shared__ __align__(16) float Bbuf[2][136];
  __shared__ __align__(16) float Cbuf[2][136];
  __shared__ float dtbuf[2][64];
  const int tid  = threadIdx.x;
  const int wave = tid >> 6;
  const int c    = wave >> 2;                     // chain 0/1
  const int lane = tid & 63;
  const int j    = ((wave & 3) << 5) | (lane & 31);  // column 0..127
  const int p    = lane >> 5;                     // K-half
  const int bb   = blockIdx.x * 2 + c;            // batch element

  const float4* p1 = reinterpret_cast<const float4*>(w1T + j*128 + p*64);
  const float4* p2 = reinterpret_cast<const float4*>(w2T + j*128 + p*64);
  const float4* pa = reinterpret_cast<const float4*>(ghT + (size_t)j*128 + p*64);
  const float4* pb = reinterpret_cast<const float4*>(ghT + (size_t)(j+128)*128 + p*64);
  const float4* pc = reinterpret_cast<const float4*>(ghT + (size_t)(j+256)*128 + p*64);

  const float b1 = ode_b1[j], b2 = ode_b2[j];
  const float bh0 = gru_bh[j], bh1 = gru_bh[j+128], bh2 = gru_bh[j+256];
  float h = h0[bb*128 + j];
  if ((tid & 255) < 64) {
    const int cc = tid >> 8, tt = tid & 63;
    dtbuf[cc][tt] = inputs[((size_t)(blockIdx.x*2 + cc)*64 + tt)*NIN + 10132];
  }
  if (p == 0) Cbuf[c][j] = h;
  const float* gib = gi_ws + (size_t)bb*64*384 + j;
  __syncthreads();

  float* A  = Abuf[c];
  float* Bv = Bbuf[c];
  float* Cv = Cbuf[c];

  auto mv = [&](const float* __restrict__ src, const float4* __restrict__ Wp, float bias)->float {
    const float4* s4 = reinterpret_cast<const float4*>(src + p*64);
    float a0=0.f,a1=0.f,a2=0.f,a3=0.f;
    #pragma unroll
    for (int q=0;q<16;q++){
      float4 hv = s4[q], wv = Wp[q];
      a0 = fmaf(hv.x, wv.x, a0);
      a1 = fmaf(hv.y, wv.y, a1);
      a2 = fmaf(hv.z, wv.z, a2);
      a3 = fmaf(hv.w, wv.w, a3);
    }
    return fast_tanh(half_reduce((a0+a1)+(a2+a3)) + bias);
  };

  for (int t=0; t<64; t++) {
    // this step's gi (L2-resident; floats across lgkm-only barriers)
    const float gir = gib[(size_t)t*384];
    const float giz = gib[(size_t)t*384 + 128];
    const float gin = gib[(size_t)t*384 + 256];
    const float dt = dtbuf[c][t];

    float u, k1, k2, k3, k4;
    u  = mv(Cv, p1, b1); if (!p) A[j] = u;                      LBAR();
    k1 = mv(A,  p2, b2); if (!p) Bv[j] = fmaf(0.5f*dt, k1, h);  LBAR();
    u  = mv(Bv, p1, b1); if (!p) A[j] = u;                      LBAR();
    k2 = mv(A,  p2, b2); if (!p) Bv[j] = fmaf(0.5f*dt, k2, h);  LBAR();
    u  = mv(Bv, p1, b1); if (!p) A[j] = u;                      LBAR();
    k3 = mv(A,  p2, b2); if (!p) Bv[j] = fmaf(dt, k3, h);       LBAR();
    u  = mv(Bv, p1, b1); if (!p) A[j] = u;                      LBAR();
    k4 = mv(A,  p2, b2);
    const float h_ode = fmaf(dt*(1.f/6.f), (k1 + 2.f*k2) + (2.f*k3 + k4), h);
    if (!p) Bv[j] = h_ode;                                      LBAR();

    // gh = h_ode @ gru_wh (3 columns per thread, K-half per lane)
    {
      const float4* h4 = reinterpret_cast<const float4*>(Bv + p*64);
      float g0=0.f, g1=0.f, g2=0.f;
      #pragma unroll
      for (int q=0;q<16;q++){
        float4 hv = h4[q];
        float4 av = pa[q], bv = pb[q], cv = pc[q];
        g0 = fmaf(hv.x, av.x, g0); g0 = fmaf(hv.y, av.y, g0);
        g0 = fmaf(hv.z, av.z, g0); g0 = fmaf(hv.w, av.w, g0);
        g1 = fmaf(hv.x, bv.x, g1); g1 = fmaf(hv.y, bv.y, g1);
        g1 = fmaf(hv.z, bv.z, g1); g1 = fmaf(hv.w, bv.w, g1);
        g2 = fmaf(hv.x, cv.x, g2); g2 = fmaf(hv.y, cv.y, g2);
        g2 = fmaf(hv.z, cv.z, g2); g2 = fmaf(hv.w, cv.w, g2);
      }
      g0 = half_reduce(g0);
      g1 = half_reduce(g1);
      g2 = half_reduce(g2);

      const float r = fast_sig(gir + g0 + bh0);
      const float z = fast_sig(giz + g1 + bh1);
      const float n = fast_tanh(gin + r*(g2 + bh2));
      h = (1.f - z)*n + z*h_ode;
    }
    if (!p) {
      Cv[j] = h;
      hs_ws[((size_t)bb*64 + t)*128 + j] = h;   // fire-and-forget
    }
    LBAR();
  }
  if (!p) hT_out[bb*128 + j] = h;
}

// ---------------- K3: logits + mask + value ----------------
__global__ __launch_bounds__(256) void k_head(const float* __restrict__ hs_ws,
    const float* __restrict__ act_w, const float* __restrict__ act_b,
    const float* __restrict__ val_w, const float* __restrict__ val_b,
    const float* __restrict__ inputs, float* __restrict__ out_logits, float* __restrict__ out_val)
{
  __shared__ float xr[16][128];
  const int tid = threadIdx.x;
  const int bt0 = blockIdx.x * 16;
  for (int idx = tid; idx < 16*128; idx += 256) {
    int r = idx >> 7, f = idx & 127;
    xr[r][f] = hs_ws[(size_t)(bt0+r)*128 + f];
  }
  __syncthreads();
  if (tid < 132) {
    float acc[16];
    float bj = act_b[tid];
    #pragma unroll
    for (int r=0;r<16;r++) acc[r] = bj;
    for (int f=0; f<128; f++) {
      float wf = act_w[f*132 + tid];
      #pragma unroll
      for (int r=0;r<16;r++) acc[r] = fmaf(xr[r][f], wf, acc[r]);
    }
    #pragma unroll
    for (int r=0;r<16;r++) {
      float mval = inputs[(size_t)(bt0+r)*NIN + tid];
      out_logits[(size_t)(bt0+r)*132 + tid] = (mval == 0.f) ? -1e10f : acc[r];
    }
  } else if (tid >= 136 && tid < 152) {
    int r = tid - 136;
    float acc = val_b[0];
    for (int f=0; f<128; f++) acc = fmaf(xr[r][f], val_w[f], acc);
    out_val[bt0 + r] = acc;
  }
}

extern "C" void kernel_launch(void* const* d_in, const int* in_sizes, int n_in,
                              void* d_out, int out_size, void* d_ws, size_t ws_size,
                              hipStream_t stream) {
  (void)in_sizes; (void)n_in; (void)out_size; (void)ws_size;
  const float* inputs = (const float*)d_in[0];
  const float* h0     = (const float*)d_in[1];
  const float* fc_w   = (const float*)d_in[2];
  const float* fc_b   = (const float*)d_in[3];
  const float* gat_w  = (const float*)d_in[4];
  const float* a_src  = (const float*)d_in[5];
  const float* a_dst  = (const float*)d_in[6];
  const float* ode_w1 = (const float*)d_in[7];
  const float* ode_b1 = (const float*)d_in[8];
  const float* ode_w2 = (const float*)d_in[9];
  const float* ode_b2 = (const float*)d_in[10];
  const float* gru_wi = (const float*)d_in[11];
  const float* gru_wh = (const float*)d_in[12];
  const float* gru_bi = (const float*)d_in[13];
  const float* gru_bh = (const float*)d_in[14];
  const float* act_w  = (const float*)d_in[15];
  const float* act_b  = (const float*)d_in[16];
  const float* val_w  = (const float*)d_in[17];
  const float* val_b  = (const float*)d_in[18];

  float* ws   = (float*)d_ws;
  float* wh0  = ws;               // 2048*128 = 262144
  float* sd   = ws + 262144;      // 2048*8   = 16384
  float* gi   = ws + 278528;      // 2048*384 = 786432
  float* hs   = ws + 1064960;     // 2048*128 = 262144
  float* w1T  = ws + 1327104;     // 128*128  = 16384
  float* w2T  = ws + 1343488;     // 128*128  = 16384
  float* ghT  = ws + 1359872;     // 384*128  = 49152

  float* out        = (float*)d_out;
  float* out_logits = out;            // 2048*132
  float* out_hT     = out + 270336;   // 32*128
  float* out_val    = out + 274432;   // 2048

  k_fc_gat  <<<dim3(128),  dim3(256), 0, stream>>>(inputs, fc_w, fc_b, gat_w, a_src, a_dst,
                                                   ode_w1, ode_w2, gru_wh,
                                                   wh0, sd, w1T, w2T, ghT);
  k_alpha_gi<<<dim3(2048), dim3(256), 0, stream>>>(inputs, wh0, sd, gru_wi, gru_bi, gi);
  k_rnn     <<<dim3(16),   dim3(512), 0, stream>>>(inputs, h0, w1T, ode_b1, w2T, ode_b2,
                                                   ghT, gru_bh, gi, hs, out_hT);
  k_head    <<<dim3(128),  dim3(256), 0, stream>>>(hs, act_w, act_b, val_w, val_b, inputs,
                                                   out_logits, out_val);
}

// Round 11
// 851.215 us; speedup vs baseline: 2.9404x; 2.9404x over previous
//
#include <hip/hip_runtime.h>

#define NIN 10517

__device__ __forceinline__ float lrelu02(float x){ return x > 0.f ? x : 0.2f*x; }
__device__ __forceinline__ float fast_tanh(float x){ float e=__expf(2.f*x); return 1.f - 2.f/(e+1.f); }
__device__ __forceinline__ float fast_sig(float x){ return 1.f/(1.f+__expf(-x)); }

// Sum across the 8 K-octant lanes (lane ^8 via ds_swizzle, ^16/^32 via
// permlane swaps — the ^16/^32 asm is r5-validated).
__device__ __forceinline__ float oct_reduce(float a){
  a += __int_as_float(__builtin_amdgcn_ds_swizzle(__float_as_int(a), 0x201F)); // lane^8
  float s;
  asm volatile("v_mov_b32 %0, %1\n\t"
               "v_permlane16_swap_b32 %0, %1\n\t"
               "v_add_f32 %1, %0, %1"
               : "=&v"(s), "+v"(a));
  asm volatile("v_mov_b32 %0, %1\n\t"
               "v_permlane32_swap_b32 %0, %1\n\t"
               "v_add_f32 %1, %0, %1"
               : "=&v"(s), "+v"(a));
  return a;
}

// light barrier: order LDS writes->reads without draining vmcnt (weight/gi
// loads and hs stores float across phases)
#define LBAR() do { asm volatile("s_waitcnt lgkmcnt(0)" ::: "memory"); \
                    __builtin_amdgcn_s_barrier(); } while (0)

// padded h-buffer index: 16-float chunks padded by 4 dwords so the 8 octant
// broadcast-read groups land on 8 disjoint bank quads
#define IDX(k) ((k) + (((k) >> 4) << 2))

// ---------------- K1a: FC + Wh0 + s,d (weight transposes folded in) ----------------
__global__ __launch_bounds__(256) void k_fc_gat(const float* __restrict__ inputs,
    const float* __restrict__ fc_w, const float* __restrict__ fc_b,
    const float* __restrict__ gat_w, const float* __restrict__ a_src, const float* __restrict__ a_dst,
    const float* __restrict__ ode_w1, const float* __restrict__ ode_w2, const float* __restrict__ gru_wh,
    float* __restrict__ wh0_ws, float* __restrict__ sd_ws,
    float* __restrict__ w1T, float* __restrict__ w2T, float* __restrict__ ghT)
{
  __shared__ float xin[16][384];
  __shared__ float xfc[16][256];
  __shared__ float wh[16][128];
  const int tid = threadIdx.x;
  const int bt0 = blockIdx.x * 16;

  // folded transposes: w1T[j][k]=ode_w1[k][j]; ghT[m][k]=gru_wh[k][m]
  {
    int gidx = blockIdx.x * 256 + tid;
    for (int idx = gidx; idx < 384*128; idx += 128*256) {
      int m = idx >> 7, k = idx & 127;
      ghT[idx] = gru_wh[k*384 + m];
    }
    if (gidx < 128*128) {
      int jj = gidx >> 7, k = gidx & 127;
      w1T[gidx] = ode_w1[k*128 + jj];
      w2T[gidx] = ode_w2[k*128 + jj];
    }
  }

  for (int idx = tid; idx < 16*384; idx += 256) {
    int r = idx / 384, f = idx - r*384;
    xin[r][f] = inputs[(size_t)(bt0+r)*NIN + 10133 + f];
  }
  __syncthreads();
  {
    float acc[16];
    float bj = fc_b[tid];
    #pragma unroll
    for (int r=0;r<16;r++) acc[r] = bj;
    for (int f=0; f<384; f++) {
      float wf = fc_w[f*256 + tid];
      #pragma unroll
      for (int r=0;r<16;r++) acc[r] = fmaf(xin[r][f], wf, acc[r]);
    }
    #pragma unroll
    for (int r=0;r<16;r++) xfc[r][tid] = fmaxf(acc[r], 0.f);
  }
  __syncthreads();
  {
    const int j2 = tid & 127, r0 = (tid >> 7) * 8;
    float acc[8];
    #pragma unroll
    for (int r=0;r<8;r++) acc[r] = 0.f;
    for (int f=0; f<256; f++) {
      float wf = gat_w[f*128 + j2];
      #pragma unroll
      for (int r=0;r<8;r++) acc[r] = fmaf(xfc[r0+r][f], wf, acc[r]);
    }
    #pragma unroll
    for (int r=0;r<8;r++) {
      wh[r0+r][j2] = acc[r];
      wh0_ws[(size_t)(bt0+r0+r)*128 + j2] = acc[r];
    }
  }
  __syncthreads();
  if (tid < 128) {
    const int r = tid >> 3, h = (tid >> 1) & 3, w = tid & 1;
    const float* av = w ? a_dst : a_src;
    float acc = 0.f;
    #pragma unroll
    for (int d=0; d<32; d++) acc = fmaf(wh[r][h*32+d], av[h*32+d], acc);
    sd_ws[(size_t)(bt0+r)*8 + w*4 + h] = acc;
  }
}

// ---------------- K1b: adjacency stats + closed-form alpha + x_gat + gi ----------------
__global__ __launch_bounds__(256) void k_alpha_gi(const float* __restrict__ inputs,
    const float* __restrict__ wh0_ws, const float* __restrict__ sd_ws,
    const float* __restrict__ gru_wi, const float* __restrict__ gru_bi,
    float* __restrict__ gi_ws)
{
  __shared__ int cnt[100];
  __shared__ int a0f[100];
  __shared__ float alpha[4][100];
  __shared__ float wh0[128];
  __shared__ float sdl[8];
  __shared__ float xg[128];
  const int tid = threadIdx.x;
  const size_t bt = blockIdx.x;
  if (tid < 128) wh0[tid] = wh0_ws[bt*128 + tid];
  if (tid < 8) sdl[tid] = sd_ws[bt*8 + tid];
  const float* adj = inputs + bt*NIN + 132;
  const int wv = tid >> 6, lane = tid & 63;
  for (int i = wv; i < 100; i += 4) {
    float v0 = adj[i*100 + lane];
    int pred0 = (lane != 0) && ((v0 > 0.f) || (lane == i));
    unsigned long long b0 = __ballot(pred0);
    int pred1 = 0;
    if (lane < 36) {
      float v1 = adj[i*100 + 64 + lane];
      pred1 = (v1 > 0.f) || ((64 + lane) == i);
    }
    unsigned long long b1 = __ballot(pred1);
    if (lane == 0) {
      cnt[i] = __popcll(b0) + __popcll(b1);
      a0f[i] = (v0 > 0.f) ? 1 : 0;
    }
  }
  __syncthreads();
  for (int idx = tid; idx < 400; idx += 256) {
    int h = idx / 100, i = idx - h*100;
    float s = sdl[h], d = sdl[4+h];
    float a;
    if (i == 0) {
      float ea = __expf(lrelu02(s + d));
      float eb = __expf(lrelu02(s));
      a = ea / (ea + (float)cnt[0] * eb);
    } else if (a0f[i]) {
      float ed = __expf(lrelu02(d));
      a = ed / (ed + (float)cnt[i]);
    } else {
      a = 0.f;
    }
    alpha[h][i] = a;
  }
  __syncthreads();
  if (tid < 128) {
    const int h = tid >> 5;
    const float w = wh0[tid];
    float sum = 0.f;
    for (int i=0;i<100;i++) {
      float t = alpha[h][i] * w;
      sum += (t > 0.f) ? t : (__expf(t) - 1.f);  // elu
    }
    xg[tid] = sum * 0.01f;  // mean over N=100
  }
  __syncthreads();
  for (int jj = tid; jj < 384; jj += 256) {
    float acc = gru_bi[jj];
    for (int f=0; f<128; f++) acc = fmaf(xg[f], gru_wi[f*384 + jj], acc);
    gi_ws[bt*384 + jj] = acc;
  }
}

// ---------------- K2: RK4-ODE + GRU scan ----------------
// 1024 threads (16 waves, 4 waves/SIMD), one block per batch element.
// Column j = wave*8 + (lane&7); K-octant p8 = lane>>3 (16 floats each).
// 4 waves/SIMD = real TLP inside each barrier-locked phase: weight-L2 waits
// and ds_read latencies of one wave overlap another's FMAs (r5/r9 had only 2
// same-phase waves/SIMD -> 864cy/phase mostly latency). Per-SIMD FMA issue
// unchanged (4 waves x 16 = 2 x 32). Reduce = ds_swizzle(^8) + permlane
// swaps. h-buffers chunk-padded so the 8 octant broadcast groups hit
// disjoint bank quads.
__global__ __launch_bounds__(1024) void k_rnn(const float* __restrict__ inputs,
    const float* __restrict__ h0,
    const float* __restrict__ w1T, const float* __restrict__ ode_b1,
    const float* __restrict__ w2T, const float* __restrict__ ode_b2,
    const float* __restrict__ ghT, const float* __restrict__ gru_bh,
    const float* __restrict__ gi_ws, float* __restrict__ hs_ws, float* __restrict__ hT_out)
{
  __shared__ __align__(16) float Abuf[160];
  __shared__ __align__(16) float Bbuf[160];
  __shared__ __align__(16) float Cbuf[160];
  __shared__ float dtbuf[64];
  const int tid = threadIdx.x;
  const int b = blockIdx.x;
  const int wave = tid >> 6, lane = tid & 63;
  const int j  = wave*8 + (lane & 7);   // output column (x8 replicated)
  const int p8 = lane >> 3;              // K-octant
  const int pj = IDX(j);

  const float4* p1 = reinterpret_cast<const float4*>(w1T + j*128 + p8*16);
  const float4* p2 = reinterpret_cast<const float4*>(w2T + j*128 + p8*16);
  const float4* pa = reinterpret_cast<const float4*>(ghT + (size_t)j*128 + p8*16);
  const float4* pb = reinterpret_cast<const float4*>(ghT + (size_t)(j+128)*128 + p8*16);
  const float4* pc = reinterpret_cast<const float4*>(ghT + (size_t)(j+256)*128 + p8*16);

  const float b1 = ode_b1[j], b2 = ode_b2[j];
  const float bh0 = gru_bh[j], bh1 = gru_bh[j+128], bh2 = gru_bh[j+256];
  float h = h0[b*128 + j];
  if (tid < 64) dtbuf[tid] = inputs[((size_t)b*64 + tid)*NIN + 10132];
  if (p8 == 0) Cbuf[pj] = h;
  const float* gib = gi_ws + (size_t)b*64*384 + j;
  __syncthreads();

  auto mv = [&](const float* __restrict__ src, const float4* __restrict__ Wp, float bias)->float {
    const float4* s4 = reinterpret_cast<const float4*>(src + 20*p8);
    float a0=0.f,a1=0.f,a2=0.f,a3=0.f;
    #pragma unroll
    for (int q=0;q<4;q++){
      float4 hv = s4[q], wv = Wp[q];
      a0 = fmaf(hv.x, wv.x, a0);
      a1 = fmaf(hv.y, wv.y, a1);
      a2 = fmaf(hv.z, wv.z, a2);
      a3 = fmaf(hv.w, wv.w, a3);
    }
    return fast_tanh(oct_reduce((a0+a1)+(a2+a3)) + bias);
  };

  for (int t=0; t<64; t++) {
    // this step's gi (L2-resident; floats across lgkm-only barriers)
    const float gir = gib[(size_t)t*384];
    const float giz = gib[(size_t)t*384 + 128];
    const float gin = gib[(size_t)t*384 + 256];
    const float dt = dtbuf[t];

    float u, k1, k2, k3, k4;
    u  = mv(Cbuf, p1, b1); if (!p8) Abuf[pj] = u;                      LBAR();
    k1 = mv(Abuf, p2, b2); if (!p8) Bbuf[pj] = fmaf(0.5f*dt, k1, h);   LBAR();
    u  = mv(Bbuf, p1, b1); if (!p8) Abuf[pj] = u;                      LBAR();
    k2 = mv(Abuf, p2, b2); if (!p8) Bbuf[pj] = fmaf(0.5f*dt, k2, h);   LBAR();
    u  = mv(Bbuf, p1, b1); if (!p8) Abuf[pj] = u;                      LBAR();
    k3 = mv(Abuf, p2, b2); if (!p8) Bbuf[pj] = fmaf(dt, k3, h);        LBAR();
    u  = mv(Bbuf, p1, b1); if (!p8) Abuf[pj] = u;                      LBAR();
    k4 = mv(Abuf, p2, b2);
    const float h_ode = fmaf(dt*(1.f/6.f), (k1 + 2.f*k2) + (2.f*k3 + k4), h);
    if (!p8) Bbuf[pj] = h_ode;                                         LBAR();

    // gh = h_ode @ gru_wh (3 columns per thread, K-octant per lane)
    {
      const float4* h4 = reinterpret_cast<const float4*>(Bbuf + 20*p8);
      float g0=0.f, g1=0.f, g2=0.f;
      #pragma unroll
      for (int q=0;q<4;q++){
        float4 hv = h4[q];
        float4 av = pa[q], bv = pb[q], cv = pc[q];
        g0 = fmaf(hv.x, av.x, g0); g0 = fmaf(hv.y, av.y, g0);
        g0 = fmaf(hv.z, av.z, g0); g0 = fmaf(hv.w, av.w, g0);
        g1 = fmaf(hv.x, bv.x, g1); g1 = fmaf(hv.y, bv.y, g1);
        g1 = fmaf(hv.z, bv.z, g1); g1 = fmaf(hv.w, bv.w, g1);
        g2 = fmaf(hv.x, cv.x, g2); g2 = fmaf(hv.y, cv.y, g2);
        g2 = fmaf(hv.z, cv.z, g2); g2 = fmaf(hv.w, cv.w, g2);
      }
      g0 = oct_reduce(g0);
      g1 = oct_reduce(g1);
      g2 = oct_reduce(g2);

      const float r = fast_sig(gir + g0 + bh0);
      const float z = fast_sig(giz + g1 + bh1);
      const float n = fast_tanh(gin + r*(g2 + bh2));
      h = (1.f - z)*n + z*h_ode;
    }
    if (!p8) {
      Cbuf[pj] = h;
      hs_ws[((size_t)b*64 + t)*128 + j] = h;   // fire-and-forget
    }
    LBAR();
  }
  if (!p8) hT_out[b*128 + j] = h;
}

// ---------------- K3: logits + mask + value ----------------
__global__ __launch_bounds__(256) void k_head(const float* __restrict__ hs_ws,
    const float* __restrict__ act_w, const float* __restrict__ act_b,
    const float* __restrict__ val_w, const float* __restrict__ val_b,
    const float* __restrict__ inputs, float* __restrict__ out_logits, float* __restrict__ out_val)
{
  __shared__ float xr[16][128];
  const int tid = threadIdx.x;
  const int bt0 = blockIdx.x * 16;
  for (int idx = tid; idx < 16*128; idx += 256) {
    int r = idx >> 7, f = idx & 127;
    xr[r][f] = hs_ws[(size_t)(bt0+r)*128 + f];
  }
  __syncthreads();
  if (tid < 132) {
    float acc[16];
    float bj = act_b[tid];
    #pragma unroll
    for (int r=0;r<16;r++) acc[r] = bj;
    for (int f=0; f<128; f++) {
      float wf = act_w[f*132 + tid];
      #pragma unroll
      for (int r=0;r<16;r++) acc[r] = fmaf(xr[r][f], wf, acc[r]);
    }
    #pragma unroll
    for (int r=0;r<16;r++) {
      float mval = inputs[(size_t)(bt0+r)*NIN + tid];
      out_logits[(size_t)(bt0+r)*132 + tid] = (mval == 0.f) ? -1e10f : acc[r];
    }
  } else if (tid >= 136 && tid < 152) {
    int r = tid - 136;
    float acc = val_b[0];
    for (int f=0; f<128; f++) acc = fmaf(xr[r][f], val_w[f], acc);
    out_val[bt0 + r] = acc;
  }
}

extern "C" void kernel_launch(void* const* d_in, const int* in_sizes, int n_in,
                              void* d_out, int out_size, void* d_ws, size_t ws_size,
                              hipStream_t stream) {
  (void)in_sizes; (void)n_in; (void)out_size; (void)ws_size;
  const float* inputs = (const float*)d_in[0];
  const float* h0     = (const float*)d_in[1];
  const float* fc_w   = (const float*)d_in[2];
  const float* fc_b   = (const float*)d_in[3];
  const float* gat_w  = (const float*)d_in[4];
  const float* a_src  = (const float*)d_in[5];
  const float* a_dst  = (const float*)d_in[6];
  const float* ode_w1 = (const float*)d_in[7];
  const float* ode_b1 = (const float*)d_in[8];
  const float* ode_w2 = (const float*)d_in[9];
  const float* ode_b2 = (const float*)d_in[10];
  const float* gru_wi = (const float*)d_in[11];
  const float* gru_wh = (const float*)d_in[12];
  const float* gru_bi = (const float*)d_in[13];
  const float* gru_bh = (const float*)d_in[14];
  const float* act_w  = (const float*)d_in[15];
  const float* act_b  = (const float*)d_in[16];
  const float* val_w  = (const float*)d_in[17];
  const float* val_b  = (const float*)d_in[18];

  float* ws   = (float*)d_ws;
  float* wh0  = ws;               // 2048*128 = 262144
  float* sd   = ws + 262144;      // 2048*8   = 16384
  float* gi   = ws + 278528;      // 2048*384 = 786432
  float* hs   = ws + 1064960;     // 2048*128 = 262144
  float* w1T  = ws + 1327104;     // 128*128  = 16384
  float* w2T  = ws + 1343488;     // 128*128  = 16384
  float* ghT  = ws + 1359872;     // 384*128  = 49152

  float* out        = (float*)d_out;
  float* out_logits = out;            // 2048*132
  float* out_hT     = out + 270336;   // 32*128
  float* out_val    = out + 274432;   // 2048

  k_fc_gat  <<<dim3(128),  dim3(256),  0, stream>>>(inputs, fc_w, fc_b, gat_w, a_src, a_dst,
                                                    ode_w1, ode_w2, gru_wh,
                                                    wh0, sd, w1T, w2T, ghT);
  k_alpha_gi<<<dim3(2048), dim3(256),  0, stream>>>(inputs, wh0, sd, gru_wi, gru_bi, gi);
  k_rnn     <<<dim3(32),   dim3(1024), 0, stream>>>(inputs, h0, w1T, ode_b1, w2T, ode_b2,
                                                    ghT, gru_bh, gi, hs, out_hT);
  k_head    <<<dim3(128),  dim3(256),  0, stream>>>(hs, act_w, act_b, val_w, val_b, inputs,
                                                    out_logits, out_val);
}

// Round 12
// 241.994 us; speedup vs baseline: 10.3430x; 3.5175x over previous
//
#include <hip/hip_runtime.h>

#define NIN 10517
typedef unsigned short ushort_t;
using f32x4  = __attribute__((ext_vector_type(4))) float;
using bf16x8 = __attribute__((ext_vector_type(8))) short;

__device__ __forceinline__ float lrelu02(float x){ return x > 0.f ? x : 0.2f*x; }
__device__ __forceinline__ float fast_tanh(float x){ float e=__expf(2.f*x); return 1.f - 2.f/(e+1.f); }
__device__ __forceinline__ float fast_sig(float x){ return 1.f/(1.f+__expf(-x)); }

// fp32 -> bf16 (round-to-nearest-even)
__device__ __forceinline__ ushort_t f2bf(float x){
  unsigned u = __float_as_uint(x);
  unsigned r = u + 0x7FFF + ((u >> 16) & 1);
  return (ushort_t)(r >> 16);
}

// light barrier: order LDS writes->reads without draining vmcnt (gi loads and
// hs stores float across phases)
#define LBAR() do { asm volatile("s_waitcnt lgkmcnt(0)" ::: "memory"); \
                    __builtin_amdgcn_s_barrier(); } while (0)

// ---------------- K1a: FC + Wh0 + s,d  (+ bf16 weight prep folded in) ----------------
__global__ __launch_bounds__(256) void k_fc_gat(const float* __restrict__ inputs,
    const float* __restrict__ fc_w, const float* __restrict__ fc_b,
    const float* __restrict__ gat_w, const float* __restrict__ a_src, const float* __restrict__ a_dst,
    const float* __restrict__ ode_w1, const float* __restrict__ ode_w2, const float* __restrict__ gru_wh,
    float* __restrict__ wh0_ws, float* __restrict__ sd_ws,
    ushort_t* __restrict__ w1B, ushort_t* __restrict__ w2B, ushort_t* __restrict__ ghB)
{
  __shared__ float xin[16][384];
  __shared__ float xfc[16][256];
  __shared__ float wh[16][128];
  const int tid = threadIdx.x;
  const int bt0 = blockIdx.x * 16;

  // bf16 weight prep: w1B[j][k]=bf16(w1[k][j]); ghB[m][k]=bf16(gru_wh[k][m])
  {
    int gidx = blockIdx.x * 256 + tid;
    for (int idx = gidx; idx < 384*128; idx += 128*256) {
      int m = idx >> 7, k = idx & 127;
      ghB[idx] = f2bf(gru_wh[k*384 + m]);
    }
    if (gidx < 128*128) {
      int jj = gidx >> 7, k = gidx & 127;
      w1B[gidx] = f2bf(ode_w1[k*128 + jj]);
      w2B[gidx] = f2bf(ode_w2[k*128 + jj]);
    }
  }

  for (int idx = tid; idx < 16*384; idx += 256) {
    int r = idx / 384, f = idx - r*384;
    xin[r][f] = inputs[(size_t)(bt0+r)*NIN + 10133 + f];
  }
  __syncthreads();
  {
    float acc[16];
    float bj = fc_b[tid];
    #pragma unroll
    for (int r=0;r<16;r++) acc[r] = bj;
    for (int f=0; f<384; f++) {
      float wf = fc_w[f*256 + tid];
      #pragma unroll
      for (int r=0;r<16;r++) acc[r] = fmaf(xin[r][f], wf, acc[r]);
    }
    #pragma unroll
    for (int r=0;r<16;r++) xfc[r][tid] = fmaxf(acc[r], 0.f);
  }
  __syncthreads();
  {
    const int j2 = tid & 127, r0 = (tid >> 7) * 8;
    float acc[8];
    #pragma unroll
    for (int r=0;r<8;r++) acc[r] = 0.f;
    for (int f=0; f<256; f++) {
      float wf = gat_w[f*128 + j2];
      #pragma unroll
      for (int r=0;r<8;r++) acc[r] = fmaf(xfc[r0+r][f], wf, acc[r]);
    }
    #pragma unroll
    for (int r=0;r<8;r++) {
      wh[r0+r][j2] = acc[r];
      wh0_ws[(size_t)(bt0+r0+r)*128 + j2] = acc[r];
    }
  }
  __syncthreads();
  if (tid < 128) {
    const int r = tid >> 3, h = (tid >> 1) & 3, w = tid & 1;
    const float* av = w ? a_dst : a_src;
    float acc = 0.f;
    #pragma unroll
    for (int d=0; d<32; d++) acc = fmaf(wh[r][h*32+d], av[h*32+d], acc);
    sd_ws[(size_t)(bt0+r)*8 + w*4 + h] = acc;
  }
}

// ---------------- K1b: adjacency stats + closed-form alpha + x_gat + gi ----------------
__global__ __launch_bounds__(256) void k_alpha_gi(const float* __restrict__ inputs,
    const float* __restrict__ wh0_ws, const float* __restrict__ sd_ws,
    const float* __restrict__ gru_wi, const float* __restrict__ gru_bi,
    float* __restrict__ gi_ws)
{
  __shared__ int cnt[100];
  __shared__ int a0f[100];
  __shared__ float alpha[4][100];
  __shared__ float wh0[128];
  __shared__ float sdl[8];
  __shared__ float xg[128];
  const int tid = threadIdx.x;
  const size_t bt = blockIdx.x;
  if (tid < 128) wh0[tid] = wh0_ws[bt*128 + tid];
  if (tid < 8) sdl[tid] = sd_ws[bt*8 + tid];
  const float* adj = inputs + bt*NIN + 132;
  const int wv = tid >> 6, lane = tid & 63;
  for (int i = wv; i < 100; i += 4) {
    float v0 = adj[i*100 + lane];
    int pred0 = (lane != 0) && ((v0 > 0.f) || (lane == i));
    unsigned long long b0 = __ballot(pred0);
    int pred1 = 0;
    if (lane < 36) {
      float v1 = adj[i*100 + 64 + lane];
      pred1 = (v1 > 0.f) || ((64 + lane) == i);
    }
    unsigned long long b1 = __ballot(pred1);
    if (lane == 0) {
      cnt[i] = __popcll(b0) + __popcll(b1);
      a0f[i] = (v0 > 0.f) ? 1 : 0;
    }
  }
  __syncthreads();
  for (int idx = tid; idx < 400; idx += 256) {
    int h = idx / 100, i = idx - h*100;
    float s = sdl[h], d = sdl[4+h];
    float a;
    if (i == 0) {
      float ea = __expf(lrelu02(s + d));
      float eb = __expf(lrelu02(s));
      a = ea / (ea + (float)cnt[0] * eb);
    } else if (a0f[i]) {
      float ed = __expf(lrelu02(d));
      a = ed / (ed + (float)cnt[i]);
    } else {
      a = 0.f;
    }
    alpha[h][i] = a;
  }
  __syncthreads();
  if (tid < 128) {
    const int h = tid >> 5;
    const float w = wh0[tid];
    float sum = 0.f;
    for (int i=0;i<100;i++) {
      float t = alpha[h][i] * w;
      sum += (t > 0.f) ? t : (__expf(t) - 1.f);  // elu
    }
    xg[tid] = sum * 0.01f;  // mean over N=100
  }
  __syncthreads();
  for (int jj = tid; jj < 384; jj += 256) {
    float acc = gru_bi[jj];
    for (int f=0; f<128; f++) acc = fmaf(xg[f], gru_wi[f*384 + jj], acc);
    gi_ws[bt*384 + jj] = acc;
  }
}

// ---------------- K2: RK4-ODE + GRU scan via MFMA ----------------
// 512 threads (8 waves), one block per batch element.
// Each matvec h@W is one wave-level MFMA chain: A-operand = h broadcast as
// ALL 16 rows (every lane then holds the valid output for col = wave*16 +
// (lane&15) in acc[0] — no reduce at all). B-operand = bf16 weight fragments
// (lane: W[k=kt*32+8*(lane>>4)+0..7][col]), loop-invariant, 16 VGPR/matvec.
// K=128 -> 4 chained MFMAs. h/RK state stays fp32; only matmul inputs are
// bf16-rounded. Per phase: 4 broadcast ds_read_b128 + 1 ds_write + 4 MFMA
// per wave (vs r5: 8 ds_read + 32 FMA + 2-stage reduce).
__global__ __launch_bounds__(512) void k_rnn(const float* __restrict__ inputs,
    const float* __restrict__ h0,
    const ushort_t* __restrict__ w1B, const float* __restrict__ ode_b1,
    const ushort_t* __restrict__ w2B, const float* __restrict__ ode_b2,
    const ushort_t* __restrict__ ghB, const float* __restrict__ gru_bh,
    const float* __restrict__ gi_ws, float* __restrict__ hs_ws, float* __restrict__ hT_out)
{
  __shared__ __align__(16) ushort_t bufA[128];
  __shared__ __align__(16) ushort_t bufB[128];
  __shared__ __align__(16) ushort_t bufC[128];
  __shared__ float dtbuf[64];
  const int tid = threadIdx.x;
  const int b = blockIdx.x;
  const int w = tid >> 6, lane = tid & 63;
  const int li = lane & 15, g = lane >> 4;
  const int col = w*16 + li;                 // output column (x4 replicated over g)

  // loop-invariant B-fragments (bf16 weights)
  bf16x8 W1f[4], W2f[4], GAf[4], GBf[4], GCf[4];
  #pragma unroll
  for (int kt=0;kt<4;kt++){
    W1f[kt] = *reinterpret_cast<const bf16x8*>(w1B + col*128       + kt*32 + g*8);
    W2f[kt] = *reinterpret_cast<const bf16x8*>(w2B + col*128       + kt*32 + g*8);
    GAf[kt] = *reinterpret_cast<const bf16x8*>(ghB + (size_t)col*128         + kt*32 + g*8);
    GBf[kt] = *reinterpret_cast<const bf16x8*>(ghB + (size_t)(col+128)*128   + kt*32 + g*8);
    GCf[kt] = *reinterpret_cast<const bf16x8*>(ghB + (size_t)(col+256)*128   + kt*32 + g*8);
  }
  const float b1 = ode_b1[col], b2 = ode_b2[col];
  const float bh0 = gru_bh[col], bh1 = gru_bh[col+128], bh2 = gru_bh[col+256];
  float h = h0[b*128 + col];                 // replicated across g
  if (tid < 64) dtbuf[tid] = inputs[((size_t)b*64 + tid)*NIN + 10132];
  if (lane < 16) bufC[col] = f2bf(h);
  const float* gib = gi_ws + (size_t)b*64*384 + col;
  __syncthreads();

  auto MV = [&](const ushort_t* __restrict__ hb, const bf16x8 (&Wf)[4], float bias)->float {
    f32x4 acc = {0.f, 0.f, 0.f, 0.f};
    #pragma unroll
    for (int kt=0;kt<4;kt++){
      bf16x8 af = *reinterpret_cast<const bf16x8*>(hb + kt*32 + g*8);  // broadcast h slice
      acc = __builtin_amdgcn_mfma_f32_16x16x32_bf16(af, Wf[kt], acc, 0, 0, 0);
    }
    // all A-rows identical -> acc[0] is valid out[col] on EVERY lane
    return fast_tanh(acc[0] + bias);
  };

  for (int t=0; t<64; t++) {
    const float dt = dtbuf[t];
    // this step's gi (global; floats across lgkm-only barriers until use)
    const float gir = gib[(size_t)t*384];
    const float giz = gib[(size_t)t*384 + 128];
    const float gin = gib[(size_t)t*384 + 256];

    float u, k1, k2, k3, k4;
    u  = MV(bufC, W1f, b1); if (lane<16) bufA[col] = f2bf(u);                      LBAR();
    k1 = MV(bufA, W2f, b2); if (lane<16) bufB[col] = f2bf(fmaf(0.5f*dt, k1, h));   LBAR();
    u  = MV(bufB, W1f, b1); if (lane<16) bufA[col] = f2bf(u);                      LBAR();
    k2 = MV(bufA, W2f, b2); if (lane<16) bufB[col] = f2bf(fmaf(0.5f*dt, k2, h));   LBAR();
    u  = MV(bufB, W1f, b1); if (lane<16) bufA[col] = f2bf(u);                      LBAR();
    k3 = MV(bufA, W2f, b2); if (lane<16) bufB[col] = f2bf(fmaf(dt, k3, h));        LBAR();
    u  = MV(bufB, W1f, b1); if (lane<16) bufA[col] = f2bf(u);                      LBAR();
    k4 = MV(bufA, W2f, b2);
    const float h_ode = fmaf(dt*(1.f/6.f), (k1 + 2.f*k2) + (2.f*k3 + k4), h);
    if (lane<16) bufB[col] = f2bf(h_ode);                                          LBAR();

    // gh = h_ode @ gru_wh : 3 independent MFMA chains (cols col, col+128, col+256)
    {
      f32x4 a0 = {0.f,0.f,0.f,0.f}, a1 = {0.f,0.f,0.f,0.f}, a2 = {0.f,0.f,0.f,0.f};
      #pragma unroll
      for (int kt=0;kt<4;kt++){
        bf16x8 af = *reinterpret_cast<const bf16x8*>(bufB + kt*32 + g*8);
        a0 = __builtin_amdgcn_mfma_f32_16x16x32_bf16(af, GAf[kt], a0, 0, 0, 0);
        a1 = __builtin_amdgcn_mfma_f32_16x16x32_bf16(af, GBf[kt], a1, 0, 0, 0);
        a2 = __builtin_amdgcn_mfma_f32_16x16x32_bf16(af, GCf[kt], a2, 0, 0, 0);
      }
      const float r = fast_sig(gir + a0[0] + bh0);
      const float z = fast_sig(giz + a1[0] + bh1);
      const float n = fast_tanh(gin + r*(a2[0] + bh2));
      h = (1.f - z)*n + z*h_ode;
    }
    if (lane < 16) {
      bufC[col] = f2bf(h);
      hs_ws[((size_t)b*64 + t)*128 + col] = h;   // fire-and-forget
    }
    LBAR();
  }
  if (lane < 16) hT_out[b*128 + col] = h;
}

// ---------------- K3: logits + mask + value ----------------
__global__ __launch_bounds__(256) void k_head(const float* __restrict__ hs_ws,
    const float* __restrict__ act_w, const float* __restrict__ act_b,
    const float* __restrict__ val_w, const float* __restrict__ val_b,
    const float* __restrict__ inputs, float* __restrict__ out_logits, float* __restrict__ out_val)
{
  __shared__ float xr[16][128];
  const int tid = threadIdx.x;
  const int bt0 = blockIdx.x * 16;
  for (int idx = tid; idx < 16*128; idx += 256) {
    int r = idx >> 7, f = idx & 127;
    xr[r][f] = hs_ws[(size_t)(bt0+r)*128 + f];
  }
  __syncthreads();
  if (tid < 132) {
    float acc[16];
    float bj = act_b[tid];
    #pragma unroll
    for (int r=0;r<16;r++) acc[r] = bj;
    for (int f=0; f<128; f++) {
      float wf = act_w[f*132 + tid];
      #pragma unroll
      for (int r=0;r<16;r++) acc[r] = fmaf(xr[r][f], wf, acc[r]);
    }
    #pragma unroll
    for (int r=0;r<16;r++) {
      float mval = inputs[(size_t)(bt0+r)*NIN + tid];
      out_logits[(size_t)(bt0+r)*132 + tid] = (mval == 0.f) ? -1e10f : acc[r];
    }
  } else if (tid >= 136 && tid < 152) {
    int r = tid - 136;
    float acc = val_b[0];
    for (int f=0; f<128; f++) acc = fmaf(xr[r][f], val_w[f], acc);
    out_val[bt0 + r] = acc;
  }
}

extern "C" void kernel_launch(void* const* d_in, const int* in_sizes, int n_in,
                              void* d_out, int out_size, void* d_ws, size_t ws_size,
                              hipStream_t stream) {
  (void)in_sizes; (void)n_in; (void)out_size; (void)ws_size;
  const float* inputs = (const float*)d_in[0];
  const float* h0     = (const float*)d_in[1];
  const float* fc_w   = (const float*)d_in[2];
  const float* fc_b   = (const float*)d_in[3];
  const float* gat_w  = (const float*)d_in[4];
  const float* a_src  = (const float*)d_in[5];
  const float* a_dst  = (const float*)d_in[6];
  const float* ode_w1 = (const float*)d_in[7];
  const float* ode_b1 = (const float*)d_in[8];
  const float* ode_w2 = (const float*)d_in[9];
  const float* ode_b2 = (const float*)d_in[10];
  const float* gru_wi = (const float*)d_in[11];
  const float* gru_wh = (const float*)d_in[12];
  const float* gru_bi = (const float*)d_in[13];
  const float* gru_bh = (const float*)d_in[14];
  const float* act_w  = (const float*)d_in[15];
  const float* act_b  = (const float*)d_in[16];
  const float* val_w  = (const float*)d_in[17];
  const float* val_b  = (const float*)d_in[18];

  float* ws   = (float*)d_ws;
  float* wh0  = ws;               // 2048*128 = 262144 floats
  float* sd   = ws + 262144;      // 2048*8
  float* gi   = ws + 278528;      // 2048*384
  float* hs   = ws + 1064960;     // 2048*128
  ushort_t* w1B = (ushort_t*)(ws + 1327104);  // 128*128 ushort = 8192 floats
  ushort_t* w2B = (ushort_t*)(ws + 1335296);  // 128*128 ushort
  ushort_t* ghB = (ushort_t*)(ws + 1343488);  // 384*128 ushort = 24576 floats

  float* out        = (float*)d_out;
  float* out_logits = out;            // 2048*132
  float* out_hT     = out + 270336;   // 32*128
  float* out_val    = out + 274432;   // 2048

  k_fc_gat  <<<dim3(128),  dim3(256), 0, stream>>>(inputs, fc_w, fc_b, gat_w, a_src, a_dst,
                                                   ode_w1, ode_w2, gru_wh,
                                                   wh0, sd, w1B, w2B, ghB);
  k_alpha_gi<<<dim3(2048), dim3(256), 0, stream>>>(inputs, wh0, sd, gru_wi, gru_bi, gi);
  k_rnn     <<<dim3(32),   dim3(512), 0, stream>>>(inputs, h0, w1B, ode_b1, w2B, ode_b2,
                                                   ghB, gru_bh, gi, hs, out_hT);
  k_head    <<<dim3(128),  dim3(256), 0, stream>>>(hs, act_w, act_b, val_w, val_b, inputs,
                                                   out_logits, out_val);
}